// Round 11
// baseline (218.233 us; speedup 1.0000x reference)
//
#include <hip/hip_runtime.h>
#include <hip/hip_bf16.h>

typedef __attribute__((ext_vector_type(8))) short sh8;
typedef __attribute__((ext_vector_type(4))) float f32x4;

#define MFMA16(a, b, c) __builtin_amdgcn_mfma_f32_16x16x32_bf16((a), (b), (c), 0, 0, 0)

__device__ __forceinline__ unsigned short f2bf(float f) {
    return (unsigned short)((__float_as_uint(f) + 0x8000u) >> 16);
}
__device__ __forceinline__ unsigned int pack2bf(float lo, float hi) {
    unsigned int ul = __float_as_uint(lo) + 0x8000u;
    unsigned int uh = __float_as_uint(hi) + 0x8000u;
    return __builtin_amdgcn_perm(uh, ul, 0x07060302u);
}
__device__ __forceinline__ float redmax_hi(float x) {
    x = fmaxf(x, __shfl_xor(x, 16, 64));
    return fmaxf(x, __shfl_xor(x, 32, 64));
}
__device__ __forceinline__ float redsum_hi(float x) {
    x += __shfl_xor(x, 16, 64);
    return x + __shfl_xor(x, 32, 64);
}
// async global->LDS, 16B per lane; LDS dest = wave-uniform base + lane*16
__device__ __forceinline__ void gload_lds16(const void* g, void* l) {
    __builtin_amdgcn_global_load_lds(
        (const __attribute__((address_space(1))) unsigned int*)g,
        (__attribute__((address_space(3))) unsigned int*)l, 16, 0, 0);
}

// ---------------------------------------------------------------------------
// f32 -> bf16 converters (run once)
// ---------------------------------------------------------------------------
__global__ __launch_bounds__(256) void cvt_x_k(
    const float* __restrict__ src, unsigned short* __restrict__ dst, int n4)
{
    int i = blockIdx.x * 256 + threadIdx.x;
    int stride = gridDim.x * 256;
    for (; i < n4; i += stride) {
        float4 v = ((const float4*)src)[i];
        uint2 h = { pack2bf(v.x, v.y), pack2bf(v.z, v.w) };
        ((uint2*)dst)[i] = h;
    }
}
__global__ __launch_bounds__(256) void cvt_w_k(
    const float* __restrict__ Wq, const float* __restrict__ Wk,
    const float* __restrict__ Wv, const float* __restrict__ Wo,
    unsigned short* __restrict__ wbf)
{
    int i = blockIdx.x * 256 + threadIdx.x;   // over 4*262144 float4s
    int seg = i >> 18;
    int off = i & 0x3FFFF;
    const float* s = (seg < 2) ? ((seg == 0) ? Wq : Wk) : ((seg == 2) ? Wv : Wo);
    float4 v = ((const float4*)s)[off];
    uint2 h = { pack2bf(v.x, v.y), pack2bf(v.z, v.w) };
    ((uint2*)wbf)[i] = h;
}

// ---------------------------------------------------------------------------
// Mask compaction (unchanged): list of kv indices with mask!=0.
// ---------------------------------------------------------------------------
__global__ __launch_bounds__(64) void compact_k(
    const int* __restrict__ mask, int* __restrict__ idx, int* __restrict__ cnt)
{
    const int b = blockIdx.x, l = threadIdx.x;
    const int* mb = mask + b * 2048;
    int base = 0;
    for (int i = 0; i < 32; ++i) {
        int m = mb[i * 64 + l];
        unsigned long long bal = __ballot(m != 0);
        int pre = __popcll(bal & ((1ull << l) - 1ull));
        if (m) idx[b * 2048 + base + pre] = i * 64 + l;
        base += (int)__popcll(bal);
    }
    if (base == 0) {
        for (int i = l; i < 2048; i += 64) idx[b * 2048 + i] = i;
        base = 2048;
    }
    if (l == 0) cnt[b] = base;
}

// ---------------------------------------------------------------------------
// Gather compacted K|V rows into dense Kc[b][i][2048] (once per batch).
// ---------------------------------------------------------------------------
__global__ __launch_bounds__(256) void kvgather_k(
    const unsigned short* __restrict__ qkv, const int* __restrict__ idx,
    const int* __restrict__ cnt, unsigned short* __restrict__ Kc, int b0)
{
    const int b = blockIdx.z;
    const int t = blockIdx.y;
    const int z = blockIdx.x;
    const int nc = cnt[b0 + b];
    if (t * 64 >= ((nc + 63) & ~63)) return;
    const int* idxb = idx + (size_t)(b0 + b) * 2048;
    const int tid = threadIdx.x;
    unsigned short* dst_b = Kc + (size_t)b * 2048 * 2048;
#pragma unroll
    for (int p = 0; p < 8; ++p) {
        int row = t * 64 + z * 8 + p;
        int src = idxb[min(row, nc - 1)];
        uint4 v = *(const uint4*)&qkv[((size_t)b * 2048 + src) * 3072 + 1024 + tid * 8];
        *(uint4*)&dst_b[(size_t)row * 2048 + tid * 8] = v;
    }
}

// ---------------------------------------------------------------------------
// R11: transpose gathered V (Kc cols 1024..2047) -> Vtg[b][h][d=64][kv=2048].
// Natural little-endian layout of contiguous kv == the pair-packed content
// attn's old in-loop repack produced; done ONCE per batch instead of by
// every attn block every tile. LDS-staged for coalescing on both sides.
// ---------------------------------------------------------------------------
__global__ __launch_bounds__(256) void vtrans_k(
    const unsigned short* __restrict__ Kc, unsigned short* __restrict__ Vtg)
{
    __shared__ unsigned short Ls[128][72];
    const int kb = blockIdx.x;      // kv block of 128
    const int h  = blockIdx.y;
    const int b  = blockIdx.z;
    const int tid = threadIdx.x;
    const unsigned short* src = Kc + (size_t)b * 2048 * 2048 + 1024 + h * 64;
#pragma unroll
    for (int p = 0; p < 4; ++p) {
        int i = p * 256 + tid;
        int r = i >> 3, c = i & 7;
        uint4 v = *(const uint4*)&src[((size_t)(kb * 128 + r)) * 2048 + c * 8];
        *(uint4*)&Ls[r][c * 8] = v;
    }
    __syncthreads();
    unsigned short* dst = Vtg + ((size_t)b * 16 + h) * 64 * 2048;
#pragma unroll
    for (int p = 0; p < 4; ++p) {
        int i = p * 256 + tid;
        int d = i >> 4, kc = i & 15;
        unsigned int wv[4];
#pragma unroll
        for (int j = 0; j < 4; ++j) {
            unsigned int lo = Ls[kc * 8 + 2 * j][d];
            unsigned int hv = Ls[kc * 8 + 2 * j + 1][d];
            wv[j] = lo | (hv << 16);
        }
        *(uint4*)&dst[(size_t)d * 2048 + kb * 128 + kc * 8] = *(uint4*)wv;
    }
}

// ---------------------------------------------------------------------------
// QKV projection, m97-style (unchanged).
// ---------------------------------------------------------------------------
__global__ __launch_bounds__(256) void gemm_qkv_k(
    const unsigned short* __restrict__ xbf,
    const unsigned short* __restrict__ wbf,
    unsigned short* __restrict__ qkv)
{
    __shared__ unsigned short As[128][32];
    __shared__ unsigned short Bs[128][32];
    const int tid = threadIdx.x;
    const int l = tid & 63, w = tid >> 6;
    const int wr = w >> 1, wc = w & 1;
    const long row0 = (long)blockIdx.y * 128;
    const int col0 = blockIdx.x * 128;

    f32x4 acc[4][4] = {};
    const int fr = l & 15, hi = l >> 4;

    const int sr = tid >> 2;
    const int sc = (tid & 3) * 8;
    const unsigned short* ga = &xbf[(row0 + sr) * 1024 + sc];
    const unsigned short* gb = &wbf[(long)(col0 + sr) * 1024 + sc];
    unsigned short* la = &As[w * 16][0];
    unsigned short* lb = &Bs[w * 16][0];

    for (int k0 = 0; k0 < 1024; k0 += 32) {
        __syncthreads();
        gload_lds16(ga + k0, la);
        gload_lds16(ga + 64 * 1024 + k0, la + 64 * 32);
        gload_lds16(gb + k0, lb);
        gload_lds16(gb + 64 * 1024 + k0, lb + 64 * 32);
        __syncthreads();

        sh8 af[4], bf[4];
#pragma unroll
        for (int i = 0; i < 4; ++i) {
            af[i] = *(const sh8*)&As[wr * 64 + i * 16 + fr][hi * 8];
            bf[i] = *(const sh8*)&Bs[wc * 64 + i * 16 + fr][hi * 8];
        }
#pragma unroll
        for (int i = 0; i < 4; ++i)
#pragma unroll
            for (int j = 0; j < 4; ++j)
                acc[i][j] = MFMA16(af[i], bf[j], acc[i][j]);
    }

    const float scale = (col0 < 1024) ? 0.1803368801f : 1.0f;
    const int rg = hi * 4, cg = l & 15;
#pragma unroll
    for (int i = 0; i < 4; ++i)
#pragma unroll
        for (int j = 0; j < 4; ++j) {
            long gr = row0 + wr * 64 + i * 16 + rg;
            int gc = col0 + wc * 64 + j * 16 + cg;
#pragma unroll
            for (int r = 0; r < 4; ++r)
                qkv[(gr + r) * 3072 + gc] = f2bf(acc[i][j][r] * scale);
        }
}

// ---------------------------------------------------------------------------
// Flash attention. R11: BOTH K and V staged via global_load_lds (linear dest,
// XOR chunk-swizzle pre-applied to per-lane SOURCE). All per-tile staging
// VALU (gather math, V repack, reg round-trips) eliminated; per tile the
// staging is 4 gload + 2 pointer bumps. Compute/softmax unchanged.
// ---------------------------------------------------------------------------
__global__ __launch_bounds__(256) void attn_k(
    const unsigned short* __restrict__ qkv, const unsigned short* __restrict__ Kc,
    const unsigned short* __restrict__ Vtg, const int* __restrict__ cnt,
    unsigned short* __restrict__ ao, int b0)
{
    __shared__ unsigned short Kl[64][64];
    __shared__ unsigned short Vt[64][64];
    __shared__ float biasf[64];
    __shared__ unsigned short Pl[4][16][72];

    const int tid = threadIdx.x;
    const int l = tid & 63, w = tid >> 6;
    const int fr = l & 15, hi = l >> 4;

    // T1: bijective XCD swizzle
    int nwg = gridDim.x;
    int wgid = ((nwg & 7) == 0) ? ((blockIdx.x & 7) * (nwg >> 3) + (blockIdx.x >> 3))
                                : blockIdx.x;
    const int qb = wgid & 31;
    const int h  = (wgid >> 5) & 15;
    const int b  = wgid >> 9;
    const int q0 = qb * 64;
    const long base = (long)b * 2048;

    const int nc = cnt[b0 + b];
    const int nt = (nc + 63) >> 6;

    sh8 qf0, qf1;
    {
        const unsigned short* qp = &qkv[(base + q0 + w * 16 + fr) * 3072 + h * 64 + hi * 8];
        qf0 = *(const sh8*)qp;
        qf1 = *(const sh8*)(qp + 32);
    }

    f32x4 acc[4] = {};
    float mrow = -1e30f;
    float lrow = 0.f;

    const long TS = 262144;                       // 64 rows * 4096 B per K tile
    const char* kc_b = (const char*)Kc + (size_t)b * 2048 * 4096;

    // K gload: lane covers LDS slot (row8 = l>>3, chunk = l&7); source chunk
    // = (l&7)^(l>>3) so LDS holds content chunk c' = global chunk c'^(r&7).
    const int l8 = l >> 3, c8 = l & 7;
    const char* ksrc = kc_b + (size_t)(w * 16 + l8) * 4096 + h * 128 + ((c8 ^ l8) * 16);
    unsigned short* kdst0 = &Kl[w * 16][0];
    unsigned short* kdst1 = &Kl[w * 16 + 8][0];

    // V gload from transposed Vtg: wave w stages d rows w*16..w*16+15;
    // source chunk pre-swizzled by fd = (d&7)^(d>>3).
    const char* vtg_h = (const char*)Vtg + ((size_t)b * 16 + h) * 64 * 4096;
    const int d0 = w * 16 + l8, d1 = d0 + 8;
    const int fd0 = (d0 & 7) ^ (d0 >> 3), fd1 = (d1 & 7) ^ (d1 >> 3);
    const char* vsrc0 = vtg_h + (size_t)d0 * 4096 + ((c8 ^ fd0) * 16);
    const char* vsrc1 = vtg_h + (size_t)d1 * 4096 + ((c8 ^ fd1) * 16);
    unsigned short* vdst0 = &Vt[w * 16][0];
    unsigned short* vdst1 = &Vt[w * 16 + 8][0];

    for (int t = 0; t < nt; ++t) {
        __syncthreads();                  // prior tile's LDS reads done
        gload_lds16(ksrc, kdst0);
        gload_lds16(ksrc + 8 * 4096, kdst1);
        ksrc += TS;
        gload_lds16(vsrc0, vdst0);
        gload_lds16(vsrc1, vdst1);
        vsrc0 += 128; vsrc1 += 128;
        if (tid < 64) biasf[tid] = (t * 64 + tid < nc) ? 0.0f : -1e9f;
        __syncthreads();                  // vmcnt drained: tiles resident

        // K fragments
        sh8 kf[4][2];
#pragma unroll
        for (int tt = 0; tt < 4; ++tt) {
            const unsigned short* kp = &Kl[tt * 16 + fr][0];
#pragma unroll
            for (int c = 0; c < 2; ++c)
                kf[tt][c] = *(const sh8*)&kp[((4 * c + hi) ^ (fr & 7)) * 8];
        }

        // S^T = K Q
        f32x4 s[4] = {};
        __builtin_amdgcn_s_setprio(1);
#pragma unroll
        for (int tt = 0; tt < 4; ++tt) {
            s[tt] = MFMA16(kf[tt][0], qf0, s[tt]);
            s[tt] = MFMA16(kf[tt][1], qf1, s[tt]);
        }
        __builtin_amdgcn_s_setprio(0);
#pragma unroll
        for (int tt = 0; tt < 4; ++tt)
            s[tt] += *(const f32x4*)&biasf[tt * 16 + 4 * hi];

        float pm = s[0][0];
#pragma unroll
        for (int tt = 0; tt < 4; ++tt)
#pragma unroll
            for (int r = 0; r < 4; ++r) pm = fmaxf(pm, s[tt][r]);
        pm = redmax_hi(pm);

        if (!__all(pm <= mrow)) {           // defer-max: wave-uniform skip
            float mn = fmaxf(mrow, pm);
            float scl = __builtin_amdgcn_exp2f(mrow - mn);
            lrow *= scl;
#pragma unroll
            for (int df = 0; df < 4; ++df) acc[df] *= scl;
            mrow = mn;
        }

        float ps = 0.f;
#pragma unroll
        for (int tt = 0; tt < 4; ++tt)
#pragma unroll
            for (int r = 0; r < 4; ++r) {
                float p = __builtin_amdgcn_exp2f(s[tt][r] - mrow);
                s[tt][r] = p;
                ps += p;
            }
        lrow += redsum_hi(ps);

        // P -> per-wave LDS (4x b64)
#pragma unroll
        for (int tt = 0; tt < 4; ++tt) {
            uint2 pw = { pack2bf(s[tt][0], s[tt][1]), pack2bf(s[tt][2], s[tt][3]) };
            *(uint2*)&Pl[w][fr][tt * 16 + hi * 4] = pw;
        }

        // O^T += V^T * P
#pragma unroll
        for (int c = 0; c < 2; ++c) {
            sh8 pa = *(const sh8*)&Pl[w][fr][c * 32 + hi * 8];
            __builtin_amdgcn_s_setprio(1);
#pragma unroll
            for (int df = 0; df < 4; ++df) {
                int d = df * 16 + fr;
                int fd = (d & 7) ^ (d >> 3);
                sh8 vfr = *(const sh8*)&Vt[d][((4 * c + hi) ^ fd) * 8];
                acc[df] = MFMA16(vfr, pa, acc[df]);
            }
            __builtin_amdgcn_s_setprio(0);
        }
    }

    {
        float inv = 1.0f / lrow;
        long qr = base + q0 + w * 16 + fr;
        unsigned short* op = &ao[qr * 1024 + h * 64];
#pragma unroll
        for (int df = 0; df < 4; ++df) {
            f32x4 o = acc[df];
            uint2 ow = { pack2bf(o[0] * inv, o[1] * inv), pack2bf(o[2] * inv, o[3] * inv) };
            *(uint2*)&op[df * 16 + hi * 4] = ow;
        }
    }
}

// ---------------------------------------------------------------------------
// Output projection, m97-style staging (unchanged).
// ---------------------------------------------------------------------------
__global__ __launch_bounds__(256) void gemm_out_k(
    const unsigned short* __restrict__ ao, const unsigned short* __restrict__ wob,
    const float* __restrict__ bo, float* __restrict__ out)
{
    __shared__ unsigned short As[128][32];
    __shared__ unsigned short Bs[128][32];
    const int tid = threadIdx.x;
    const int l = tid & 63, w = tid >> 6;
    const int wr = w >> 1, wc = w & 1;
    const long row0 = (long)blockIdx.y * 128;
    const int col0 = blockIdx.x * 128;

    f32x4 acc[4][4] = {};
    const int fr = l & 15, hi = l >> 4;

    const int sr = tid >> 2;
    const int sc = (tid & 3) * 8;
    const unsigned short* ga = &ao[(row0 + sr) * 1024 + sc];
    const unsigned short* gb = &wob[(long)(col0 + sr) * 1024 + sc];
    unsigned short* la = &As[w * 16][0];
    unsigned short* lb = &Bs[w * 16][0];

    for (int k0 = 0; k0 < 1024; k0 += 32) {
        __syncthreads();
        gload_lds16(ga + k0, la);
        gload_lds16(ga + 64 * 1024 + k0, la + 64 * 32);
        gload_lds16(gb + k0, lb);
        gload_lds16(gb + 64 * 1024 + k0, lb + 64 * 32);
        __syncthreads();

        sh8 af[4], bf[4];
#pragma unroll
        for (int i = 0; i < 4; ++i) {
            af[i] = *(const sh8*)&As[wr * 64 + i * 16 + fr][hi * 8];
            bf[i] = *(const sh8*)&Bs[wc * 64 + i * 16 + fr][hi * 8];
        }
#pragma unroll
        for (int i = 0; i < 4; ++i)
#pragma unroll
            for (int j = 0; j < 4; ++j)
                acc[i][j] = MFMA16(af[i], bf[j], acc[i][j]);
    }

    const int rg = hi * 4, cg = l & 15;
#pragma unroll
    for (int i = 0; i < 4; ++i)
#pragma unroll
        for (int j = 0; j < 4; ++j) {
            long gr = row0 + wr * 64 + i * 16 + rg;
            int gc = col0 + wc * 64 + j * 16 + cg;
            float bb = bo[gc];
#pragma unroll
            for (int r = 0; r < 4; ++r)
                out[(gr + r) * 1024 + gc] = acc[i][j][r] + bb;
        }
}

extern "C" void kernel_launch(void* const* d_in, const int* in_sizes, int n_in,
                              void* d_out, int out_size, void* d_ws, size_t ws_size,
                              hipStream_t stream) {
    const float* x    = (const float*)d_in[0];
    const int*   mask = (const int*)d_in[1];
    const float* Wq   = (const float*)d_in[2];
    const float* Wk   = (const float*)d_in[3];
    const float* Wv   = (const float*)d_in[4];
    const float* Wo   = (const float*)d_in[5];
    const float* bo   = (const float*)d_in[6];
    float* out = (float*)d_out;

    const size_t wbf_bytes = (size_t)4096 * 1024 * 2;              // 8 MiB
    const size_t idx_bytes = (size_t)4 * 2048 * 4 + 64;
    const size_t xbf_per_b = (size_t)2048 * 1024 * 2;              // 4 MiB
    const size_t qkv_per_b = (size_t)2048 * 3072 * 2;              // 12 MiB
    const size_t ao_per_b  = (size_t)2048 * 1024 * 2;              // 4 MiB
    const size_t kc_per_b  = (size_t)2048 * 2048 * 2;              // 8 MiB
    const size_t vt_per_b  = (size_t)16 * 64 * 2048 * 2;           // 4 MiB
    const size_t per_b = xbf_per_b + qkv_per_b + ao_per_b + kc_per_b + vt_per_b; // 32 MiB

    size_t fixed = wbf_bytes + idx_bytes;
    size_t avail = (ws_size > fixed) ? (ws_size - fixed) : 0;
    int bchunk = (avail >= per_b) ? (int)(avail / per_b) : 1;
    if (bchunk > 4) bchunk = 4;

    char* p = (char*)d_ws;
    unsigned short* wbf = (unsigned short*)p;            p += wbf_bytes;
    int* idxp = (int*)p;                                 p += (size_t)4 * 2048 * 4;
    int* cntp = (int*)p;                                 p += 64;
    unsigned short* xbf = (unsigned short*)p;            p += (size_t)bchunk * xbf_per_b;
    unsigned short* qkv = (unsigned short*)p;            p += (size_t)bchunk * qkv_per_b;
    unsigned short* ao  = (unsigned short*)p;            p += (size_t)bchunk * ao_per_b;
    unsigned short* Kc  = (unsigned short*)p;            p += (size_t)bchunk * kc_per_b;
    unsigned short* Vtg = (unsigned short*)p;

    cvt_w_k<<<4096, 256, 0, stream>>>(Wq, Wk, Wv, Wo, wbf);
    compact_k<<<4, 64, 0, stream>>>(mask, idxp, cntp);

    for (int b0 = 0; b0 < 4; b0 += bchunk) {
        int bc = (4 - b0 < bchunk) ? (4 - b0) : bchunk;
        cvt_x_k<<<2048, 256, 0, stream>>>(
            x + (size_t)b0 * 2048 * 1024, xbf, bc * 524288);
        gemm_qkv_k<<<dim3(24, bc * 16), 256, 0, stream>>>(xbf, wbf, qkv);
        kvgather_k<<<dim3(8, 32, bc), 256, 0, stream>>>(qkv, idxp, cntp, Kc, b0);
        vtrans_k<<<dim3(16, 16, bc), 256, 0, stream>>>(Kc, Vtg);
        attn_k<<<dim3(512 * bc), 256, 0, stream>>>(qkv, Kc, Vtg, cntp, ao, b0);
        gemm_out_k<<<dim3(8, bc * 16), 256, 0, stream>>>(
            ao, wbf + (size_t)3072 * 1024, bo, out + (size_t)b0 * 2048 * 1024);
    }
}

// Round 12
// 213.493 us; speedup vs baseline: 1.0222x; 1.0222x over previous
//
#include <hip/hip_runtime.h>
#include <hip/hip_bf16.h>

typedef __attribute__((ext_vector_type(8))) short sh8;
typedef __attribute__((ext_vector_type(4))) float f32x4;

#define MFMA16(a, b, c) __builtin_amdgcn_mfma_f32_16x16x32_bf16((a), (b), (c), 0, 0, 0)

__device__ __forceinline__ unsigned short f2bf(float f) {
    return (unsigned short)((__float_as_uint(f) + 0x8000u) >> 16);
}
__device__ __forceinline__ unsigned int pack2bf(float lo, float hi) {
    unsigned int ul = __float_as_uint(lo) + 0x8000u;
    unsigned int uh = __float_as_uint(hi) + 0x8000u;
    return __builtin_amdgcn_perm(uh, ul, 0x07060302u);
}
__device__ __forceinline__ float redmax_hi(float x) {
    x = fmaxf(x, __shfl_xor(x, 16, 64));
    return fmaxf(x, __shfl_xor(x, 32, 64));
}
__device__ __forceinline__ float redsum_hi(float x) {
    x += __shfl_xor(x, 16, 64);
    return x + __shfl_xor(x, 32, 64);
}
// async global->LDS, 16B per lane; LDS dest = wave-uniform base + lane*16
__device__ __forceinline__ void gload_lds16(const void* g, void* l) {
    __builtin_amdgcn_global_load_lds(
        (const __attribute__((address_space(1))) unsigned int*)g,
        (__attribute__((address_space(3))) unsigned int*)l, 16, 0, 0);
}

// ---------------------------------------------------------------------------
// f32 -> bf16 converters (run once)
// ---------------------------------------------------------------------------
__global__ __launch_bounds__(256) void cvt_x_k(
    const float* __restrict__ src, unsigned short* __restrict__ dst, int n4)
{
    int i = blockIdx.x * 256 + threadIdx.x;
    int stride = gridDim.x * 256;
    for (; i < n4; i += stride) {
        float4 v = ((const float4*)src)[i];
        uint2 h = { pack2bf(v.x, v.y), pack2bf(v.z, v.w) };
        ((uint2*)dst)[i] = h;
    }
}
__global__ __launch_bounds__(256) void cvt_w_k(
    const float* __restrict__ Wq, const float* __restrict__ Wk,
    const float* __restrict__ Wv, const float* __restrict__ Wo,
    unsigned short* __restrict__ wbf)
{
    int i = blockIdx.x * 256 + threadIdx.x;   // over 4*262144 float4s
    int seg = i >> 18;
    int off = i & 0x3FFFF;
    const float* s = (seg < 2) ? ((seg == 0) ? Wq : Wk) : ((seg == 2) ? Wv : Wo);
    float4 v = ((const float4*)s)[off];
    uint2 h = { pack2bf(v.x, v.y), pack2bf(v.z, v.w) };
    ((uint2*)wbf)[i] = h;
}

// ---------------------------------------------------------------------------
// Mask compaction (unchanged): list of kv indices with mask!=0.
// ---------------------------------------------------------------------------
__global__ __launch_bounds__(64) void compact_k(
    const int* __restrict__ mask, int* __restrict__ idx, int* __restrict__ cnt)
{
    const int b = blockIdx.x, l = threadIdx.x;
    const int* mb = mask + b * 2048;
    int base = 0;
    for (int i = 0; i < 32; ++i) {
        int m = mb[i * 64 + l];
        unsigned long long bal = __ballot(m != 0);
        int pre = __popcll(bal & ((1ull << l) - 1ull));
        if (m) idx[b * 2048 + base + pre] = i * 64 + l;
        base += (int)__popcll(bal);
    }
    if (base == 0) {
        for (int i = l; i < 2048; i += 64) idx[b * 2048 + i] = i;
        base = 2048;
    }
    if (l == 0) cnt[b] = base;
}

// ---------------------------------------------------------------------------
// R12: gather compacted K rows ONLY -> Kck[b][row][1024] (4 MB/batch).
// ---------------------------------------------------------------------------
__global__ __launch_bounds__(256) void kvgather_k(
    const unsigned short* __restrict__ qkv, const int* __restrict__ idx,
    const int* __restrict__ cnt, unsigned short* __restrict__ Kck, int b0)
{
    const int b = blockIdx.z;
    const int t = blockIdx.y;
    const int z = blockIdx.x;          // row octet 0..7
    const int nc = cnt[b0 + b];
    if (t * 64 >= ((nc + 63) & ~63)) return;
    const int* idxb = idx + (size_t)(b0 + b) * 2048;
    const int tid = threadIdx.x;
    unsigned short* dst_b = Kck + (size_t)b * 2048 * 1024;
#pragma unroll
    for (int p = 0; p < 4; ++p) {
        int i = p * 256 + tid;                 // 0..1023
        int r = t * 64 + z * 8 + (i >> 7);
        int c = i & 127;
        int src = idxb[min(r, nc - 1)];
        uint4 v = *(const uint4*)&qkv[((size_t)b * 2048 + src) * 3072 + 1024 + c * 8];
        *(uint4*)&dst_b[(size_t)r * 1024 + c * 8] = v;
    }
}

// ---------------------------------------------------------------------------
// R12: gather+transpose V directly from qkv -> Vtg[b][h][d=64][kv=2048].
// (No intermediate dense V copy; one read of qkv's V-half, one write.)
// ---------------------------------------------------------------------------
__global__ __launch_bounds__(256) void vtrans_k(
    const unsigned short* __restrict__ qkv, const int* __restrict__ idx,
    const int* __restrict__ cnt, unsigned short* __restrict__ Vtg, int b0)
{
    __shared__ unsigned short Ls[128][72];
    const int kb = blockIdx.x;      // kv block of 128
    const int h  = blockIdx.y;
    const int b  = blockIdx.z;
    const int nc = cnt[b0 + b];
    if (kb * 128 >= ((nc + 63) & ~63)) return;
    const int* idxb = idx + (size_t)(b0 + b) * 2048;
    const int tid = threadIdx.x;
#pragma unroll
    for (int p = 0; p < 4; ++p) {
        int i = p * 256 + tid;
        int r = i >> 3, c = i & 7;
        int src = idxb[min(kb * 128 + r, nc - 1)];
        uint4 v = *(const uint4*)&qkv[((size_t)b * 2048 + src) * 3072 + 2048 + h * 64 + c * 8];
        *(uint4*)&Ls[r][c * 8] = v;
    }
    __syncthreads();
    unsigned short* dst = Vtg + ((size_t)b * 16 + h) * 64 * 2048;
#pragma unroll
    for (int p = 0; p < 4; ++p) {
        int i = p * 256 + tid;
        int d = i >> 4, kc = i & 15;
        unsigned int wv[4];
#pragma unroll
        for (int j = 0; j < 4; ++j) {
            unsigned int lo = Ls[kc * 8 + 2 * j][d];
            unsigned int hv = Ls[kc * 8 + 2 * j + 1][d];
            wv[j] = lo | (hv << 16);
        }
        *(uint4*)&dst[(size_t)d * 2048 + kb * 128 + kc * 8] = *(uint4*)wv;
    }
}

// ---------------------------------------------------------------------------
// QKV projection, m97-style (unchanged).
// ---------------------------------------------------------------------------
__global__ __launch_bounds__(256) void gemm_qkv_k(
    const unsigned short* __restrict__ xbf,
    const unsigned short* __restrict__ wbf,
    unsigned short* __restrict__ qkv)
{
    __shared__ unsigned short As[128][32];
    __shared__ unsigned short Bs[128][32];
    const int tid = threadIdx.x;
    const int l = tid & 63, w = tid >> 6;
    const int wr = w >> 1, wc = w & 1;
    const long row0 = (long)blockIdx.y * 128;
    const int col0 = blockIdx.x * 128;

    f32x4 acc[4][4] = {};
    const int fr = l & 15, hi = l >> 4;

    const int sr = tid >> 2;
    const int sc = (tid & 3) * 8;
    const unsigned short* ga = &xbf[(row0 + sr) * 1024 + sc];
    const unsigned short* gb = &wbf[(long)(col0 + sr) * 1024 + sc];
    unsigned short* la = &As[w * 16][0];
    unsigned short* lb = &Bs[w * 16][0];

    for (int k0 = 0; k0 < 1024; k0 += 32) {
        __syncthreads();
        gload_lds16(ga + k0, la);
        gload_lds16(ga + 64 * 1024 + k0, la + 64 * 32);
        gload_lds16(gb + k0, lb);
        gload_lds16(gb + 64 * 1024 + k0, lb + 64 * 32);
        __syncthreads();

        sh8 af[4], bf[4];
#pragma unroll
        for (int i = 0; i < 4; ++i) {
            af[i] = *(const sh8*)&As[wr * 64 + i * 16 + fr][hi * 8];
            bf[i] = *(const sh8*)&Bs[wc * 64 + i * 16 + fr][hi * 8];
        }
#pragma unroll
        for (int i = 0; i < 4; ++i)
#pragma unroll
            for (int j = 0; j < 4; ++j)
                acc[i][j] = MFMA16(af[i], bf[j], acc[i][j]);
    }

    const float scale = (col0 < 1024) ? 0.1803368801f : 1.0f;
    const int rg = hi * 4, cg = l & 15;
#pragma unroll
    for (int i = 0; i < 4; ++i)
#pragma unroll
        for (int j = 0; j < 4; ++j) {
            long gr = row0 + wr * 64 + i * 16 + rg;
            int gc = col0 + wc * 64 + j * 16 + cg;
#pragma unroll
            for (int r = 0; r < 4; ++r)
                qkv[(gr + r) * 3072 + gc] = f2bf(acc[i][j][r] * scale);
        }
}

// ---------------------------------------------------------------------------
// Flash attention. R12: K from Kck (stride 2048B), V from Vtg; both staged
// via global_load_lds with source-side XOR swizzle. Bias hoisted out of the
// loop: full tiles are all-valid by compaction, so the additive mask bias is
// applied only on the LAST tile (wave-uniform branch).
// ---------------------------------------------------------------------------
__global__ __launch_bounds__(256) void attn_k(
    const unsigned short* __restrict__ qkv, const unsigned short* __restrict__ Kck,
    const unsigned short* __restrict__ Vtg, const int* __restrict__ cnt,
    unsigned short* __restrict__ ao, int b0)
{
    __shared__ unsigned short Kl[64][64];
    __shared__ unsigned short Vt[64][64];
    __shared__ float biasf[64];
    __shared__ unsigned short Pl[4][16][72];

    const int tid = threadIdx.x;
    const int l = tid & 63, w = tid >> 6;
    const int fr = l & 15, hi = l >> 4;

    // T1: bijective XCD swizzle
    int nwg = gridDim.x;
    int wgid = ((nwg & 7) == 0) ? ((blockIdx.x & 7) * (nwg >> 3) + (blockIdx.x >> 3))
                                : blockIdx.x;
    const int qb = wgid & 31;
    const int h  = (wgid >> 5) & 15;
    const int b  = wgid >> 9;
    const int q0 = qb * 64;
    const long base = (long)b * 2048;

    const int nc = cnt[b0 + b];
    const int nt = (nc + 63) >> 6;

    sh8 qf0, qf1;
    {
        const unsigned short* qp = &qkv[(base + q0 + w * 16 + fr) * 3072 + h * 64 + hi * 8];
        qf0 = *(const sh8*)qp;
        qf1 = *(const sh8*)(qp + 32);
    }

    f32x4 acc[4] = {};
    float mrow = -1e30f;
    float lrow = 0.f;

    const long TSK = 131072;                      // 64 rows * 2048 B per K tile
    const char* kck_b = (const char*)Kck + (size_t)b * 2048 * 2048;

    // K gload: lane covers LDS slot (row8 = l>>3, chunk = l&7); source chunk
    // = (l&7)^(l>>3) so LDS holds content chunk c' = global chunk c'^(r&7).
    const int l8 = l >> 3, c8 = l & 7;
    const char* ksrc = kck_b + (size_t)(w * 16 + l8) * 2048 + h * 128 + ((c8 ^ l8) * 16);
    unsigned short* kdst0 = &Kl[w * 16][0];
    unsigned short* kdst1 = &Kl[w * 16 + 8][0];

    // V gload from transposed Vtg: wave w stages d rows w*16..w*16+15;
    // source chunk pre-swizzled by fd = (d&7)^(d>>3).
    const char* vtg_h = (const char*)Vtg + ((size_t)b * 16 + h) * 64 * 4096;
    const int d0 = w * 16 + l8, d1 = d0 + 8;
    const int fd0 = (d0 & 7) ^ (d0 >> 3), fd1 = (d1 & 7) ^ (d1 >> 3);
    const char* vsrc0 = vtg_h + (size_t)d0 * 4096 + ((c8 ^ fd0) * 16);
    const char* vsrc1 = vtg_h + (size_t)d1 * 4096 + ((c8 ^ fd1) * 16);
    unsigned short* vdst0 = &Vt[w * 16][0];
    unsigned short* vdst1 = &Vt[w * 16 + 8][0];

    // bias for the LAST tile only (full tiles all-valid by compaction)
    if (tid < 64) biasf[tid] = ((nt - 1) * 64 + tid < nc) ? 0.0f : -1e9f;

    for (int t = 0; t < nt; ++t) {
        __syncthreads();                  // prior tile's LDS reads done
        gload_lds16(ksrc, kdst0);
        gload_lds16(ksrc + 8 * 2048, kdst1);
        ksrc += TSK;
        gload_lds16(vsrc0, vdst0);
        gload_lds16(vsrc1, vdst1);
        vsrc0 += 128; vsrc1 += 128;
        __syncthreads();                  // vmcnt drained: tiles resident

        // K fragments
        sh8 kf[4][2];
#pragma unroll
        for (int tt = 0; tt < 4; ++tt) {
            const unsigned short* kp = &Kl[tt * 16 + fr][0];
#pragma unroll
            for (int c = 0; c < 2; ++c)
                kf[tt][c] = *(const sh8*)&kp[((4 * c + hi) ^ (fr & 7)) * 8];
        }

        // S^T = K Q
        f32x4 s[4] = {};
        __builtin_amdgcn_s_setprio(1);
#pragma unroll
        for (int tt = 0; tt < 4; ++tt) {
            s[tt] = MFMA16(kf[tt][0], qf0, s[tt]);
            s[tt] = MFMA16(kf[tt][1], qf1, s[tt]);
        }
        __builtin_amdgcn_s_setprio(0);

        if (t == nt - 1) {                // mask bias: last tile only
#pragma unroll
            for (int tt = 0; tt < 4; ++tt)
                s[tt] += *(const f32x4*)&biasf[tt * 16 + 4 * hi];
        }

        float pm = s[0][0];
#pragma unroll
        for (int tt = 0; tt < 4; ++tt)
#pragma unroll
            for (int r = 0; r < 4; ++r) pm = fmaxf(pm, s[tt][r]);
        pm = redmax_hi(pm);

        if (!__all(pm <= mrow)) {           // defer-max: wave-uniform skip
            float mn = fmaxf(mrow, pm);
            float scl = __builtin_amdgcn_exp2f(mrow - mn);
            lrow *= scl;
#pragma unroll
            for (int df = 0; df < 4; ++df) acc[df] *= scl;
            mrow = mn;
        }

        float ps = 0.f;
#pragma unroll
        for (int tt = 0; tt < 4; ++tt)
#pragma unroll
            for (int r = 0; r < 4; ++r) {
                float p = __builtin_amdgcn_exp2f(s[tt][r] - mrow);
                s[tt][r] = p;
                ps += p;
            }
        lrow += redsum_hi(ps);

        // P -> per-wave LDS (4x b64)
#pragma unroll
        for (int tt = 0; tt < 4; ++tt) {
            uint2 pw = { pack2bf(s[tt][0], s[tt][1]), pack2bf(s[tt][2], s[tt][3]) };
            *(uint2*)&Pl[w][fr][tt * 16 + hi * 4] = pw;
        }

        // O^T += V^T * P
#pragma unroll
        for (int c = 0; c < 2; ++c) {
            sh8 pa = *(const sh8*)&Pl[w][fr][c * 32 + hi * 8];
            __builtin_amdgcn_s_setprio(1);
#pragma unroll
            for (int df = 0; df < 4; ++df) {
                int d = df * 16 + fr;
                int fd = (d & 7) ^ (d >> 3);
                sh8 vfr = *(const sh8*)&Vt[d][((4 * c + hi) ^ fd) * 8];
                acc[df] = MFMA16(vfr, pa, acc[df]);
            }
            __builtin_amdgcn_s_setprio(0);
        }
    }

    {
        float inv = 1.0f / lrow;
        long qr = base + q0 + w * 16 + fr;
        unsigned short* op = &ao[qr * 1024 + h * 64];
#pragma unroll
        for (int df = 0; df < 4; ++df) {
            f32x4 o = acc[df];
            uint2 ow = { pack2bf(o[0] * inv, o[1] * inv), pack2bf(o[2] * inv, o[3] * inv) };
            *(uint2*)&op[df * 16 + hi * 4] = ow;
        }
    }
}

// ---------------------------------------------------------------------------
// Output projection, m97-style staging (unchanged).
// ---------------------------------------------------------------------------
__global__ __launch_bounds__(256) void gemm_out_k(
    const unsigned short* __restrict__ ao, const unsigned short* __restrict__ wob,
    const float* __restrict__ bo, float* __restrict__ out)
{
    __shared__ unsigned short As[128][32];
    __shared__ unsigned short Bs[128][32];
    const int tid = threadIdx.x;
    const int l = tid & 63, w = tid >> 6;
    const int wr = w >> 1, wc = w & 1;
    const long row0 = (long)blockIdx.y * 128;
    const int col0 = blockIdx.x * 128;

    f32x4 acc[4][4] = {};
    const int fr = l & 15, hi = l >> 4;

    const int sr = tid >> 2;
    const int sc = (tid & 3) * 8;
    const unsigned short* ga = &ao[(row0 + sr) * 1024 + sc];
    const unsigned short* gb = &wob[(long)(col0 + sr) * 1024 + sc];
    unsigned short* la = &As[w * 16][0];
    unsigned short* lb = &Bs[w * 16][0];

    for (int k0 = 0; k0 < 1024; k0 += 32) {
        __syncthreads();
        gload_lds16(ga + k0, la);
        gload_lds16(ga + 64 * 1024 + k0, la + 64 * 32);
        gload_lds16(gb + k0, lb);
        gload_lds16(gb + 64 * 1024 + k0, lb + 64 * 32);
        __syncthreads();

        sh8 af[4], bf[4];
#pragma unroll
        for (int i = 0; i < 4; ++i) {
            af[i] = *(const sh8*)&As[wr * 64 + i * 16 + fr][hi * 8];
            bf[i] = *(const sh8*)&Bs[wc * 64 + i * 16 + fr][hi * 8];
        }
#pragma unroll
        for (int i = 0; i < 4; ++i)
#pragma unroll
            for (int j = 0; j < 4; ++j)
                acc[i][j] = MFMA16(af[i], bf[j], acc[i][j]);
    }

    const int rg = hi * 4, cg = l & 15;
#pragma unroll
    for (int i = 0; i < 4; ++i)
#pragma unroll
        for (int j = 0; j < 4; ++j) {
            long gr = row0 + wr * 64 + i * 16 + rg;
            int gc = col0 + wc * 64 + j * 16 + cg;
            float bb = bo[gc];
#pragma unroll
            for (int r = 0; r < 4; ++r)
                out[(gr + r) * 1024 + gc] = acc[i][j][r] + bb;
        }
}

extern "C" void kernel_launch(void* const* d_in, const int* in_sizes, int n_in,
                              void* d_out, int out_size, void* d_ws, size_t ws_size,
                              hipStream_t stream) {
    const float* x    = (const float*)d_in[0];
    const int*   mask = (const int*)d_in[1];
    const float* Wq   = (const float*)d_in[2];
    const float* Wk   = (const float*)d_in[3];
    const float* Wv   = (const float*)d_in[4];
    const float* Wo   = (const float*)d_in[5];
    const float* bo   = (const float*)d_in[6];
    float* out = (float*)d_out;

    const size_t wbf_bytes = (size_t)4096 * 1024 * 2;              // 8 MiB
    const size_t idx_bytes = (size_t)4 * 2048 * 4 + 64;
    const size_t xbf_per_b = (size_t)2048 * 1024 * 2;              // 4 MiB
    const size_t qkv_per_b = (size_t)2048 * 3072 * 2;              // 12 MiB
    const size_t ao_per_b  = (size_t)2048 * 1024 * 2;              // 4 MiB
    const size_t kck_per_b = (size_t)2048 * 1024 * 2;              // 4 MiB
    const size_t vt_per_b  = (size_t)16 * 64 * 2048 * 2;           // 4 MiB
    const size_t per_b = xbf_per_b + qkv_per_b + ao_per_b + kck_per_b + vt_per_b; // 28 MiB

    size_t fixed = wbf_bytes + idx_bytes;
    size_t avail = (ws_size > fixed) ? (ws_size - fixed) : 0;
    int bchunk = (avail >= per_b) ? (int)(avail / per_b) : 1;
    if (bchunk > 4) bchunk = 4;

    char* p = (char*)d_ws;
    unsigned short* wbf = (unsigned short*)p;            p += wbf_bytes;
    int* idxp = (int*)p;                                 p += (size_t)4 * 2048 * 4;
    int* cntp = (int*)p;                                 p += 64;
    unsigned short* xbf = (unsigned short*)p;            p += (size_t)bchunk * xbf_per_b;
    unsigned short* qkv = (unsigned short*)p;            p += (size_t)bchunk * qkv_per_b;
    unsigned short* ao  = (unsigned short*)p;            p += (size_t)bchunk * ao_per_b;
    unsigned short* Kck = (unsigned short*)p;            p += (size_t)bchunk * kck_per_b;
    unsigned short* Vtg = (unsigned short*)p;

    cvt_w_k<<<4096, 256, 0, stream>>>(Wq, Wk, Wv, Wo, wbf);
    compact_k<<<4, 64, 0, stream>>>(mask, idxp, cntp);

    for (int b0 = 0; b0 < 4; b0 += bchunk) {
        int bc = (4 - b0 < bchunk) ? (4 - b0) : bchunk;
        cvt_x_k<<<2048, 256, 0, stream>>>(
            x + (size_t)b0 * 2048 * 1024, xbf, bc * 524288);
        gemm_qkv_k<<<dim3(24, bc * 16), 256, 0, stream>>>(xbf, wbf, qkv);
        kvgather_k<<<dim3(8, 32, bc), 256, 0, stream>>>(qkv, idxp, cntp, Kck, b0);
        vtrans_k<<<dim3(16, 16, bc), 256, 0, stream>>>(qkv, idxp, cntp, Vtg, b0);
        attn_k<<<dim3(512 * bc), 256, 0, stream>>>(qkv, Kck, Vtg, cntp, ao, b0);
        gemm_out_k<<<dim3(8, bc * 16), 256, 0, stream>>>(
            ao, wbf + (size_t)3072 * 1024, bo, out + (size_t)b0 * 2048 * 1024);
    }
}